// Round 12
// baseline (351.222 us; speedup 1.0000x reference)
//
#include <hip/hip_runtime.h>
#include <float.h>
#include <math.h>

#define HF 128
#define SCAN_CHUNK 4096  // 256 threads x 16 elems
#define NB_CSR 128       // chunks for counting-sort CSR build
#define VPACK 12500      // packed (2-per-int) node bins per range: 25000 nodes / range
#define VRANGE (2 * VPACK)
#define CS_GRID 256      // colstats_part grid (per-block partials, no atomics)

static inline int idiv(int a, int b) { return (a + b - 1) / b; }

__device__ inline unsigned short f2bf(float x) {  // RNE float->bf16
  unsigned u = __float_as_uint(x);
  return (unsigned short)((u + 0x7fffu + ((u >> 16) & 1u)) >> 16);
}
__device__ inline unsigned packbf(float a, float b) {
  return (unsigned)f2bf(a) | ((unsigned)f2bf(b) << 16);
}
#define BFLO(w) __uint_as_float((w) << 16)
#define BFHI(w) __uint_as_float((w) & 0xffff0000u)

// ---------------- CSR build: LDS-histogram counting sort (ZERO device-scope atomics) ----------------
// Round-2 evidence: 1.2M global atomics = 24.7 G/s RMW wall. Per-chunk LDS histograms
// + column scan + scatter instead.

__global__ __launch_bounds__(512) void csr_hist(const int* __restrict__ nidx,
                                                const int* __restrict__ hidx,
                                                int E, int M,
                                                int* __restrict__ HE,
                                                int* __restrict__ HV) {
  __shared__ int bins[VPACK];
  int b = blockIdx.x, y = blockIdx.y, tid = threadIdx.x;
  int chunk = (E + NB_CSR - 1) / NB_CSR;
  int e0 = b * chunk;
  int e1 = e0 + chunk; if (e1 > E) e1 = E;
  if (y == 0) {
    for (int s = tid; s < M; s += 512) bins[s] = 0;
    __syncthreads();
    for (int e = e0 + tid; e < e1; e += 512) atomicAdd(&bins[hidx[e]], 1);
    __syncthreads();
    for (int s = tid; s < M; s += 512) HE[(size_t)b * M + s] = bins[s];
  } else {
    int R = (y - 1) * VRANGE;
    int* HVr = HV + ((size_t)(y - 1) * NB_CSR + b) * VPACK;
    for (int q = tid; q < VPACK; q += 512) bins[q] = 0;
    __syncthreads();
    for (int e = e0 + tid; e < e1; e += 512) {
      int v = nidx[e] - R;
      if ((unsigned)v < (unsigned)VRANGE) atomicAdd(&bins[v >> 1], (v & 1) ? 0x10000 : 1);
    }
    __syncthreads();
    for (int q = tid; q < VPACK; q += 512) HVr[q] = bins[q];
  }
}

// Per-segment exclusive scan over the NB_CSR chunks (in place) + dense counts.
__global__ __launch_bounds__(256) void csr_colscan(int* __restrict__ HE,
                                                   int* __restrict__ HV,
                                                   int M, int N, int NVR,
                                                   int* __restrict__ cnt_e,
                                                   int* __restrict__ cnt_v) {
  int col = blockIdx.x * 256 + threadIdx.x;
  if (col < M) {
    int run = 0;
    for (int b = 0; b < NB_CSR; ++b) {
      size_t i = (size_t)b * M + col;
      int t = HE[i]; HE[i] = run; run += t;
    }
    cnt_e[col] = run;
  } else if (col < M + NVR * VPACK) {
    int c = col - M;
    int r = c / VPACK, q = c - r * VPACK;
    int* HVr = HV + (size_t)r * NB_CSR * VPACK;
    int run = 0;
    for (int b = 0; b < NB_CSR; ++b) {
      size_t i = (size_t)b * VPACK + q;
      int t = HVr[i]; HVr[i] = run; run += t;
    }
    int node = r * VRANGE + 2 * q;
    if (node < N) cnt_v[node] = run & 0xffff;
    if (node + 1 < N) cnt_v[node + 1] = run >> 16;
  }
}

// Scatter: preload LDS bins with global base (off + chunk-exclusive), LDS-atomic rank.
__global__ __launch_bounds__(512) void csr_scatter(const int* __restrict__ nidx,
                                                   const int* __restrict__ hidx,
                                                   int E, int M,
                                                   const int* __restrict__ HE,
                                                   const int* __restrict__ HV,
                                                   const int* __restrict__ off_e,
                                                   const int* __restrict__ off_v,
                                                   unsigned short* __restrict__ by_h,
                                                   unsigned short* __restrict__ by_v) {
  __shared__ int bins[VPACK];
  int b = blockIdx.x, y = blockIdx.y, tid = threadIdx.x;
  int chunk = (E + NB_CSR - 1) / NB_CSR;
  int e0 = b * chunk;
  int e1 = e0 + chunk; if (e1 > E) e1 = E;
  if (y == 0) {
    for (int s = tid; s < M; s += 512) bins[s] = off_e[s] + HE[(size_t)b * M + s];
    __syncthreads();
    for (int e = e0 + tid; e < e1; e += 512) {
      int pos = atomicAdd(&bins[hidx[e]], 1);
      by_h[pos] = (unsigned short)nidx[e];
    }
  } else {
    int R = (y - 1) * VRANGE;
    const int* HVr = HV + ((size_t)(y - 1) * NB_CSR + b) * VPACK;
    for (int q = tid; q < VPACK; q += 512) bins[q] = HVr[q];
    __syncthreads();
    for (int e = e0 + tid; e < e1; e += 512) {
      int v = nidx[e];
      int vr = v - R;
      if ((unsigned)vr < (unsigned)VRANGE) {
        int old = atomicAdd(&bins[vr >> 1], (vr & 1) ? 0x10000 : 1);
        int rank = (vr & 1) ? (old >> 16) : (old & 0xffff);
        by_v[off_v[v] + rank] = (unsigned short)hidx[e];
      }
    }
  }
}

// ---- fused 3-phase multi-block exclusive scan over both dense count arrays ----

__global__ __launch_bounds__(256) void scanA2(const int* __restrict__ inE, int nE, int nbE,
                                              int* __restrict__ partE,
                                              const int* __restrict__ inV, int nV,
                                              int* __restrict__ partV) {
  const int* in; int n, b; int* partials;
  if ((int)blockIdx.x < nbE) { in = inE; n = nE; b = blockIdx.x; partials = partE; }
  else { in = inV; n = nV; b = blockIdx.x - nbE; partials = partV; }
  __shared__ int lds[256];
  int tid = threadIdx.x;
  int base = b * SCAN_CHUNK + tid * 16;
  int s = 0;
#pragma unroll
  for (int i = 0; i < 16; ++i) {
    int idx = base + i;
    if (idx < n) s += in[idx];
  }
  lds[tid] = s;
  __syncthreads();
  for (int off = 128; off; off >>= 1) {
    if (tid < off) lds[tid] += lds[tid + off];
    __syncthreads();
  }
  if (tid == 0) partials[b] = lds[0];
}

__global__ __launch_bounds__(256) void scanB2(int* __restrict__ partE, int nbE,
                                              int* __restrict__ partV, int nbV) {
  int* partials = (blockIdx.x == 0) ? partE : partV;
  int nb = (blockIdx.x == 0) ? nbE : nbV;
  __shared__ int lds[256];
  int tid = threadIdx.x;
  int v = (tid < nb) ? partials[tid] : 0;
  lds[tid] = v;
  __syncthreads();
  for (int off = 1; off < 256; off <<= 1) {
    int add = (tid >= off) ? lds[tid - off] : 0;
    __syncthreads();
    lds[tid] += add;
    __syncthreads();
  }
  if (tid < nb) partials[tid] = lds[tid] - v;  // exclusive
  if (tid == nb - 1) partials[nb] = lds[tid];  // total
}

__global__ __launch_bounds__(256) void scanC2(const int* __restrict__ inE, int nE, int nbE,
                                              const int* __restrict__ partE, int* __restrict__ outE,
                                              const int* __restrict__ inV, int nV, int nbV,
                                              const int* __restrict__ partV, int* __restrict__ outV) {
  const int* in; const int* partials; int* out; int n, b, nb;
  if ((int)blockIdx.x < nbE) { in = inE; n = nE; b = blockIdx.x; partials = partE; out = outE; nb = nbE; }
  else { in = inV; n = nV; b = blockIdx.x - nbE; partials = partV; out = outV; nb = nbV; }
  __shared__ int lds[256];
  int tid = threadIdx.x;
  int base = b * SCAN_CHUNK + tid * 16;
  int vals[16];
  int s = 0;
#pragma unroll
  for (int i = 0; i < 16; ++i) {
    int idx = base + i;
    int v = (idx < n) ? in[idx] : 0;
    vals[i] = s;
    s += v;
  }
  lds[tid] = s;
  __syncthreads();
  int own = s;
  for (int off = 1; off < 256; off <<= 1) {
    int add = (tid >= off) ? lds[tid - off] : 0;
    __syncthreads();
    lds[tid] += add;
    __syncthreads();
  }
  int excl = lds[tid] - own + partials[b];
#pragma unroll
  for (int i = 0; i < 16; ++i) {
    int idx = base + i;
    if (idx < n) out[idx] = excl + vals[i];
  }
  if (b == 0 && tid == 0) out[n] = partials[nb];
}

// wqt = Wq^T * (1/sqrt(128)) [score scale folded]; wcat[:,128:256] = Wv.
__global__ void prep_att(const float* __restrict__ Wq, const float* __restrict__ Wv,
                         float* __restrict__ wqt, float* __restrict__ wcat) {
  int i = blockIdx.x * blockDim.x + threadIdx.x;  // 128*128
  if (i >= 128 * 128) return;
  int r = i >> 7, c = i & 127;
  wqt[c * 128 + r] = Wq[i] * 0.08838834764831845f;
  wcat[r * 256 + 128 + c] = Wv[i];
}

// ---------------- GEMM: 64x64 tile, 4x4 micro, single LDS buffer (round-9 form) ----------------
// Round-10/11 evidence: LDS dbuf (occ 41->24%) regressed; register prefetch neutral.
// At ~41% occupancy wave-level TLP already hides staging latency -> keep the simple
// single-buffer form (best measured).

__device__ __forceinline__ void gemm64_body(const float* __restrict__ A,
                                            const float* __restrict__ W,
                                            const float* __restrict__ bias,
                                            float* __restrict__ out,
                                            int R, int K, int C, int act,
                                            const float* __restrict__ insc,
                                            const float* __restrict__ insh, int inact,
                                            int ldo, int obf16,
                                            unsigned short* __restrict__ out16,
                                            int bx, int by) {
  __shared__ __align__(16) float As[64][20];
  __shared__ __align__(16) float Bs[16][64];
  int tid = threadIdx.x;
  int tx = tid & 15;
  int ty = tid >> 4;
  int rowBase = bx * 64;
  int colBase = by * 64;

  float acc[4][4] = {};

  for (int k0 = 0; k0 < K; k0 += 16) {
    {
      int arow = tid >> 2, ac = (tid & 3) * 4;
      int gr = rowBase + arow;
      float4 av = make_float4(0.f, 0.f, 0.f, 0.f);
      if (gr < R) av = *(const float4*)(A + (size_t)gr * K + k0 + ac);
      if (insc) {
        float vv[4] = {av.x, av.y, av.z, av.w};
#pragma unroll
        for (int i = 0; i < 4; ++i) {
          float s = insc[k0 + ac + i], sh = insh[k0 + ac + i];
          float v = vv[i] * s + sh;
          if (inact) v = v > 0.f ? v : 0.01f * v;
          vv[i] = v;
        }
        av = make_float4(vv[0], vv[1], vv[2], vv[3]);
      }
      *(float4*)&As[arow][ac] = av;
    }
    {
      int bk = tid >> 4, bc = (tid & 15) * 4;
      *(float4*)&Bs[bk][bc] = *(const float4*)(W + (size_t)(k0 + bk) * C + colBase + bc);
    }
    __syncthreads();
#pragma unroll
    for (int kg = 0; kg < 16; kg += 4) {
      float af[4][4], bf[4][4];
#pragma unroll
      for (int i = 0; i < 4; ++i)
        *(float4*)af[i] = *(const float4*)&As[ty * 4 + i][kg];
#pragma unroll
      for (int kk = 0; kk < 4; ++kk)
        *(float4*)bf[kk] = *(const float4*)&Bs[kg + kk][tx * 4];
#pragma unroll
      for (int kk = 0; kk < 4; ++kk)
#pragma unroll
        for (int i = 0; i < 4; ++i)
#pragma unroll
          for (int j = 0; j < 4; ++j)
            acc[i][j] = fmaf(af[i][kk], bf[kk][j], acc[i][j]);
    }
    __syncthreads();
  }

#pragma unroll
  for (int i = 0; i < 4; ++i) {
    int r = rowBase + ty * 4 + i;
    if (r >= R) continue;
    float vals[4];
#pragma unroll
    for (int j = 0; j < 4; ++j) {
      float v = acc[i][j];
      if (bias) v += bias[colBase + tx * 4 + j];
      if (act) v = v > 0.f ? v : 0.01f * v;
      vals[j] = v;
    }
    if (obf16) {
      unsigned short* o16 = (unsigned short*)out;
      ushort4 w = make_ushort4(f2bf(vals[0]), f2bf(vals[1]), f2bf(vals[2]), f2bf(vals[3]));
      *(ushort4*)(o16 + (size_t)r * ldo + colBase + tx * 4) = w;
    } else {
      *(float4*)(out + (size_t)r * ldo + colBase + tx * 4) =
          make_float4(vals[0], vals[1], vals[2], vals[3]);
      if (out16) {
        uint2 w = make_uint2(packbf(vals[0], vals[1]), packbf(vals[2], vals[3]));
        *(uint2*)(out16 + (size_t)r * ldo + colBase + tx * 4) = w;
      }
    }
  }
}

struct GArgs {
  const float* A; const float* W; const float* bias; float* out;
  int R, K, C, act;
  const float* insc; const float* insh; int inact, ldo, obf16;
  unsigned short* out16;
  int nbx, nb;   // nbx = idiv(R,64); nb = nbx * ncols
};

__global__ __launch_bounds__(256) void gemm64(GArgs g) {
  gemm64_body(g.A, g.W, g.bias, g.out, g.R, g.K, g.C, g.act, g.insc, g.insh, g.inact,
              g.ldo, g.obf16, g.out16, blockIdx.x % g.nbx, blockIdx.x / g.nbx);
}

// Horizontal fusion of up to 3 independent GEMMs (identical body -> identical
// resources; block->arg selection is wave-uniform SGPR work).
__global__ __launch_bounds__(256) void gemm64_multi(GArgs g0, GArgs g1, GArgs g2) {
  int b = blockIdx.x;
  GArgs g = g0;
  if (b >= g0.nb) {
    b -= g0.nb;
    if (b < g1.nb) g = g1;
    else { b -= g1.nb; g = g2; }
  }
  gemm64_body(g.A, g.W, g.bias, g.out, g.R, g.K, g.C, g.act, g.insc, g.insh, g.inact,
              g.ldo, g.obf16, g.out16, b % g.nbx, b / g.nbx);
}

// ---------------- segment ops: one wave per segment; 4 x 16-lane groups, 8 feats/lane ----------------
// Round-6/7 evidence: 2-deep idx/data pipeline gained ~8us on the seg gathers (kept).

__device__ __forceinline__ void seg_mean_e_body(const unsigned short* __restrict__ h16,
                                                const int* __restrict__ off_e,
                                                const unsigned short* __restrict__ by_h,
                                                unsigned short* __restrict__ m_e16, int M, int bx) {
  int m = (bx * 256 + (int)threadIdx.x) >> 6;
  if (m >= M) return;
  int lane = threadIdx.x & 63;
  int g = lane >> 4;
  int fl = lane & 15;
  int s = off_e[m], e1 = off_e[m + 1];
  float4 a0 = make_float4(0.f, 0.f, 0.f, 0.f), a1 = a0;
  uint4 z4 = make_uint4(0, 0, 0, 0);
  int j = s + g;
  int iC = (j + 8 < e1) ? by_h[j + 8] : 0;
  uint4 hwA = z4, hwB = z4;
  if (j < e1) {
    int i0 = by_h[j];
    hwA = *(const uint4*)(h16 + (size_t)i0 * HF + fl * 8);
  }
  if (j + 4 < e1) {
    int i1 = by_h[j + 4];
    hwB = *(const uint4*)(h16 + (size_t)i1 * HF + fl * 8);
  }
  while (j < e1) {
    uint4 hwC = z4;
    if (j + 8 < e1) hwC = *(const uint4*)(h16 + (size_t)iC * HF + fl * 8);
    int iD = (j + 12 < e1) ? by_h[j + 12] : 0;
    a0.x += BFLO(hwA.x); a0.y += BFHI(hwA.x); a0.z += BFLO(hwA.y); a0.w += BFHI(hwA.y);
    a1.x += BFLO(hwA.z); a1.y += BFHI(hwA.z); a1.z += BFLO(hwA.w); a1.w += BFHI(hwA.w);
    hwA = hwB; hwB = hwC; iC = iD;
    j += 4;
  }
#pragma unroll
  for (int mask = 16; mask <= 32; mask <<= 1) {
    a0.x += __shfl_xor(a0.x, mask); a0.y += __shfl_xor(a0.y, mask);
    a0.z += __shfl_xor(a0.z, mask); a0.w += __shfl_xor(a0.w, mask);
    a1.x += __shfl_xor(a1.x, mask); a1.y += __shfl_xor(a1.y, mask);
    a1.z += __shfl_xor(a1.z, mask); a1.w += __shfl_xor(a1.w, mask);
  }
  if (g == 0) {
    int cnt = e1 - s;
    float r = 1.f / (float)(cnt > 0 ? cnt : 1);
    uint4 w = make_uint4(packbf(a0.x * r, a0.y * r), packbf(a0.z * r, a0.w * r),
                         packbf(a1.x * r, a1.y * r), packbf(a1.z * r, a1.w * r));
    *(uint4*)(m_e16 + (size_t)m * HF + fl * 8) = w;
  }
}

// Phase-B fusion: her2 GEMM blocks + seg_mean_e gather blocks (complementary pipes).
__global__ __launch_bounds__(256) void gemm_segmean(GArgs g,
                                                    const unsigned short* __restrict__ h16,
                                                    const int* __restrict__ off_e,
                                                    const unsigned short* __restrict__ by_h,
                                                    unsigned short* __restrict__ m_e16, int M) {
  int b = blockIdx.x;
  if (b < g.nb) {
    gemm64_body(g.A, g.W, g.bias, g.out, g.R, g.K, g.C, g.act, g.insc, g.insh, g.inact,
                g.ldo, g.obf16, g.out16, b % g.nbx, b / g.nbx);
    return;
  }
  seg_mean_e_body(h16, off_e, by_h, m_e16, M, b - g.nb);
}

__device__ __forceinline__ void seg_mean_v_body(float* __restrict__ h,
                                                const unsigned short* __restrict__ m_e16,
                                                const int* __restrict__ off_v,
                                                const unsigned short* __restrict__ by_v,
                                                int N, int bx) {
  int n = (bx * 256 + (int)threadIdx.x) >> 6;
  if (n >= N) return;
  int lane = threadIdx.x & 63;
  int g = lane >> 4;
  int fl = lane & 15;
  int s = off_v[n], e1 = off_v[n + 1];
  float4 a0 = make_float4(0.f, 0.f, 0.f, 0.f), a1 = a0;
  uint4 z4 = make_uint4(0, 0, 0, 0);
  int j = s + g;
  int iC = (j + 8 < e1) ? by_v[j + 8] : 0;
  uint4 hwA = z4, hwB = z4;
  if (j < e1) {
    int i0 = by_v[j];
    hwA = *(const uint4*)(m_e16 + (size_t)i0 * HF + fl * 8);
  }
  if (j + 4 < e1) {
    int i1 = by_v[j + 4];
    hwB = *(const uint4*)(m_e16 + (size_t)i1 * HF + fl * 8);
  }
  while (j < e1) {
    uint4 hwC = z4;
    if (j + 8 < e1) hwC = *(const uint4*)(m_e16 + (size_t)iC * HF + fl * 8);
    int iD = (j + 12 < e1) ? by_v[j + 12] : 0;
    a0.x += BFLO(hwA.x); a0.y += BFHI(hwA.x); a0.z += BFLO(hwA.y); a0.w += BFHI(hwA.y);
    a1.x += BFLO(hwA.z); a1.y += BFHI(hwA.z); a1.z += BFLO(hwA.w); a1.w += BFHI(hwA.w);
    hwA = hwB; hwB = hwC; iC = iD;
    j += 4;
  }
#pragma unroll
  for (int mask = 16; mask <= 32; mask <<= 1) {
    a0.x += __shfl_xor(a0.x, mask); a0.y += __shfl_xor(a0.y, mask);
    a0.z += __shfl_xor(a0.z, mask); a0.w += __shfl_xor(a0.w, mask);
    a1.x += __shfl_xor(a1.x, mask); a1.y += __shfl_xor(a1.y, mask);
    a1.z += __shfl_xor(a1.z, mask); a1.w += __shfl_xor(a1.w, mask);
  }
  if (g == 0) {
    int cnt = e1 - s;
    float r = 1.f / (float)(cnt > 0 ? cnt : 1);
    float* hp = h + (size_t)n * HF + fl * 8;
    float4 h0 = *(const float4*)hp;
    float4 h1 = *(const float4*)(hp + 4);
    *(float4*)hp = make_float4(h0.x + a0.x * r, h0.y + a0.y * r, h0.z + a0.z * r, h0.w + a0.w * r);
    *(float4*)(hp + 4) = make_float4(h1.x + a1.x * r, h1.y + a1.y * r, h1.z + a1.z * r, h1.w + a1.w * r);
  }
}

// Phase-B2 fusion: kv projection GEMM blocks + seg_mean_v_add gather blocks.
// (Round-12: kv moved out of phase C so it overlaps a latency-bound gather instead
// of competing with the sr2 GEMM for VALU issue.)
__global__ __launch_bounds__(256) void gemm_segmeanv(GArgs g,
                                                     float* __restrict__ h,
                                                     const unsigned short* __restrict__ m_e16,
                                                     const int* __restrict__ off_v,
                                                     const unsigned short* __restrict__ by_v,
                                                     int N) {
  int b = blockIdx.x;
  if (b < g.nb) {
    gemm64_body(g.A, g.W, g.bias, g.out, g.R, g.K, g.C, g.act, g.insc, g.insh, g.inact,
                g.ldo, g.obf16, g.out16, b % g.nbx, b / g.nbx);
    return;
  }
  seg_mean_v_body(h, m_e16, off_v, by_v, N, b - g.nb);
}

// Fused GAT attention: one wave per node; q = h2 (fp32, score scale pre-folded into Wqk);
// kv bf16 [M][256]; software prefetch + defer-max rescale (THR=8).
// Round-7/8 evidence: this 4x16 one-deep form is the measured optimum (41.6us). Kept.
__global__ __launch_bounds__(256) void att_fused(const float* __restrict__ q,
                                                 const unsigned short* __restrict__ kv,
                                                 const int* __restrict__ off_v,
                                                 const unsigned short* __restrict__ by_v,
                                                 unsigned short* __restrict__ ho16, int N) {
  int n = (blockIdx.x * blockDim.x + threadIdx.x) >> 6;
  if (n >= N) return;
  int lane = threadIdx.x & 63;
  int g = lane >> 4;
  int fl = lane & 15;
  int s0 = off_v[n], s1 = off_v[n + 1];
  const float* qp = q + (size_t)n * HF + fl * 8;
  float4 q0 = *(const float4*)qp;
  float4 q1 = *(const float4*)(qp + 4);
  float m = -INFINITY, l = 0.f;
  float4 a0 = make_float4(0.f, 0.f, 0.f, 0.f), a1 = a0;
  int j = s0 + g;
  uint4 kw = make_uint4(0, 0, 0, 0), vw = kw;
  if (j < s1) {
    const unsigned short* base = kv + (size_t)by_v[j] * 256 + fl * 8;
    kw = *(const uint4*)base;
    vw = *(const uint4*)(base + 128);
  }
  while (j < s1) {
    int jn = j + 4;
    uint4 kw2 = make_uint4(0, 0, 0, 0), vw2 = kw2;
    if (jn < s1) {
      const unsigned short* b2 = kv + (size_t)by_v[jn] * 256 + fl * 8;
      kw2 = *(const uint4*)b2;
      vw2 = *(const uint4*)(b2 + 128);
    }
    float d = q0.x * BFLO(kw.x) + q0.y * BFHI(kw.x) + q0.z * BFLO(kw.y) + q0.w * BFHI(kw.y)
            + q1.x * BFLO(kw.z) + q1.y * BFHI(kw.z) + q1.z * BFLO(kw.w) + q1.w * BFHI(kw.w);
    d += __shfl_xor(d, 1);
    d += __shfl_xor(d, 2);
    d += __shfl_xor(d, 4);
    d += __shfl_xor(d, 8);
    d = d > 0.f ? d : 0.2f * d;   // scale already folded into Wqk
    if (d > m + 8.f) {
      float sc = __expf(m - d);   // first edge: exp(-inf)=0 zeroes l,a
      l *= sc;
      a0.x *= sc; a0.y *= sc; a0.z *= sc; a0.w *= sc;
      a1.x *= sc; a1.y *= sc; a1.z *= sc; a1.w *= sc;
      m = d;
    }
    float p = __expf(d - m);
    l += p;
    a0.x += p * BFLO(vw.x); a0.y += p * BFHI(vw.x);
    a0.z += p * BFLO(vw.y); a0.w += p * BFHI(vw.y);
    a1.x += p * BFLO(vw.z); a1.y += p * BFHI(vw.z);
    a1.z += p * BFLO(vw.w); a1.w += p * BFHI(vw.w);
    kw = kw2; vw = vw2; j = jn;
  }
#pragma unroll
  for (int mask = 16; mask <= 32; mask <<= 1) {
    float m2 = __shfl_xor(m, mask);
    float l2 = __shfl_xor(l, mask);
    float b0x = __shfl_xor(a0.x, mask), b0y = __shfl_xor(a0.y, mask);
    float b0z = __shfl_xor(a0.z, mask), b0w = __shfl_xor(a0.w, mask);
    float b1x = __shfl_xor(a1.x, mask), b1y = __shfl_xor(a1.y, mask);
    float b1z = __shfl_xor(a1.z, mask), b1w = __shfl_xor(a1.w, mask);
    float mn = fmaxf(fmaxf(m, m2), -1e30f);
    float ea = __expf(m - mn), eb = __expf(m2 - mn);
    l = l * ea + l2 * eb;
    a0.x = a0.x * ea + b0x * eb; a0.y = a0.y * ea + b0y * eb;
    a0.z = a0.z * ea + b0z * eb; a0.w = a0.w * ea + b0w * eb;
    a1.x = a1.x * ea + b1x * eb; a1.y = a1.y * ea + b1y * eb;
    a1.z = a1.z * ea + b1z * eb; a1.w = a1.w * ea + b1w * eb;
    m = fmaxf(m, m2);
  }
  if (g == 0) {
    float inv = 1.f / fmaxf(l, 1e-16f);
    uint4 w = make_uint4(packbf(a0.x * inv, a0.y * inv), packbf(a0.z * inv, a0.w * inv),
                         packbf(a1.x * inv, a1.y * inv), packbf(a1.z * inv, a1.w * inv));
    *(uint4*)(ho16 + (size_t)n * HF + fl * 8) = w;
  }
}

// z[m][0:128] = segment_min(ho16[node]) (0 if empty); z[m][128:256] = xe[m]
__global__ __launch_bounds__(256) void seg_min_z(const unsigned short* __restrict__ ho16,
                                                 const int* __restrict__ off_e,
                                                 const unsigned short* __restrict__ by_h,
                                                 const float* __restrict__ xe,
                                                 float* __restrict__ z, int M) {
  int m = (blockIdx.x * blockDim.x + threadIdx.x) >> 6;
  if (m >= M) return;
  int lane = threadIdx.x & 63;
  int g = lane >> 4;
  int fl = lane & 15;
  int s = off_e[m], e1 = off_e[m + 1];
  float4 a0 = make_float4(FLT_MAX, FLT_MAX, FLT_MAX, FLT_MAX), a1 = a0;
  uint4 z4 = make_uint4(0, 0, 0, 0);
  int j = s + g;
  int iC = (j + 8 < e1) ? by_h[j + 8] : 0;
  uint4 hwA = z4, hwB = z4;
  if (j < e1) {
    int i0 = by_h[j];
    hwA = *(const uint4*)(ho16 + (size_t)i0 * HF + fl * 8);
  }
  if (j + 4 < e1) {
    int i1 = by_h[j + 4];
    hwB = *(const uint4*)(ho16 + (size_t)i1 * HF + fl * 8);
  }
  while (j < e1) {
    uint4 hwC = z4;
    if (j + 8 < e1) hwC = *(const uint4*)(ho16 + (size_t)iC * HF + fl * 8);
    int iD = (j + 12 < e1) ? by_h[j + 12] : 0;
    a0.x = fminf(a0.x, BFLO(hwA.x)); a0.y = fminf(a0.y, BFHI(hwA.x));
    a0.z = fminf(a0.z, BFLO(hwA.y)); a0.w = fminf(a0.w, BFHI(hwA.y));
    a1.x = fminf(a1.x, BFLO(hwA.z)); a1.y = fminf(a1.y, BFHI(hwA.z));
    a1.z = fminf(a1.z, BFLO(hwA.w)); a1.w = fminf(a1.w, BFHI(hwA.w));
    hwA = hwB; hwB = hwC; iC = iD;
    j += 4;
  }
#pragma unroll
  for (int mask = 16; mask <= 32; mask <<= 1) {
    a0.x = fminf(a0.x, __shfl_xor(a0.x, mask)); a0.y = fminf(a0.y, __shfl_xor(a0.y, mask));
    a0.z = fminf(a0.z, __shfl_xor(a0.z, mask)); a0.w = fminf(a0.w, __shfl_xor(a0.w, mask));
    a1.x = fminf(a1.x, __shfl_xor(a1.x, mask)); a1.y = fminf(a1.y, __shfl_xor(a1.y, mask));
    a1.z = fminf(a1.z, __shfl_xor(a1.z, mask)); a1.w = fminf(a1.w, __shfl_xor(a1.w, mask));
  }
  if (g == 0) {
    bool nz = (e1 > s);
    float* op = z + (size_t)m * 256 + fl * 8;
    *(float4*)op = nz ? a0 : make_float4(0.f, 0.f, 0.f, 0.f);
    *(float4*)(op + 4) = nz ? a1 : make_float4(0.f, 0.f, 0.f, 0.f);
  } else if (g == 1) {
    const float* xp = xe + (size_t)m * HF + fl * 8;
    float* op = z + (size_t)m * 256 + 128 + fl * 8;
    *(float4*)op = *(const float4*)xp;
    *(float4*)(op + 4) = *(const float4*)(xp + 4);
  }
}

// ---------------- GraphNorm stats: two-kernel deterministic reduction ----------------

__global__ __launch_bounds__(1024) void colstats_part(const float* __restrict__ z, int rows, int C,
                                                      float* __restrict__ part) {
  int tid = threadIdx.x;
  int RL = 1024 / C;
  int col = tid & (C - 1);
  int ro = tid / C;
  float s1 = 0.f, s2 = 0.f;
  for (int r = blockIdx.x * RL + ro; r < rows; r += gridDim.x * RL) {
    float v = z[(size_t)r * C + col];
    s1 += v;
    s2 += v * v;
  }
  __shared__ float l1[1024], l2[1024];
  l1[tid] = s1;
  l2[tid] = s2;
  __syncthreads();
  for (int off = 512; off >= C; off >>= 1) {
    if (tid < off) { l1[tid] += l1[tid + off]; l2[tid] += l2[tid + off]; }
    __syncthreads();
  }
  if (tid < C) {
    part[(size_t)blockIdx.x * 2 * C + tid] = l1[tid];
    part[(size_t)blockIdx.x * 2 * C + C + tid] = l2[tid];
  }
}

__global__ void colstats_fin(const float* __restrict__ part, int nb, int C,
                             const float* __restrict__ w, const float* __restrict__ b,
                             const float* __restrict__ a, float invrows,
                             float* __restrict__ sc, float* __restrict__ sh) {
  int col = threadIdx.x;
  if (col >= C) return;
  float s1 = 0.f, s2 = 0.f;
#pragma unroll 8
  for (int i = 0; i < nb; ++i) {
    s1 += part[(size_t)i * 2 * C + col];
    s2 += part[(size_t)i * 2 * C + C + col];
  }
  float mu = s1 * invrows;
  float ex2 = s2 * invrows;
  float av = a[col];
  float var = ex2 - 2.f * av * mu * mu + av * av * mu * mu;
  float s = w[col] * rsqrtf(var + 1e-5f);
  sc[col] = s;
  sh[col] = b[col] - av * mu * s;
}

// ---------------- launch ----------------

extern "C" void kernel_launch(void* const* d_in, const int* in_sizes, int n_in,
                              void* d_out, int out_size, void* d_ws, size_t ws_size,
                              hipStream_t stream) {
  const float* x        = (const float*)d_in[0];
  const float* x_e      = (const float*)d_in[2];
  const int*   node_idx = (const int*)d_in[3];
  const int*   hedge_idx= (const int*)d_in[4];
  const float* her_W1   = (const float*)d_in[5];
  const float* her_b1   = (const float*)d_in[6];
  const float* her_W2   = (const float*)d_in[7];
  const float* her_b2   = (const float*)d_in[8];
  const float* sr_W1    = (const float*)d_in[9];
  const float* sr_b1    = (const float*)d_in[10];
  const float* sr_W2    = (const float*)d_in[11];
  const float* sr_b2    = (const float*)d_in[12];
  const float* att_Wq   = (const float*)d_in[13];
  const float* att_Wk   = (const float*)d_in[14];
  const float* att_Wv   = (const float*)d_in[15];
  const float* ef_W     = (const float*)d_in[16];
  const float* ef_b     = (const float*)d_in[17];
  const float* gn1_w    = (const float*)d_in[18];
  const float* gn1_b    = (const float*)d_in[19];
  const float* gn1_a    = (const float*)d_in[20];
  const float* gn2_w    = (const float*)d_in[21];
  const float* gn2_b    = (const float*)d_in[22];
  const float* gn2_a    = (const float*)d_in[23];
  const float* cls_W1   = (const float*)d_in[24];
  const float* cls_b1   = (const float*)d_in[25];
  const float* cls_W2   = (const float*)d_in[26];
  const float* cls_b2   = (const float*)d_in[27];

  const int N = in_sizes[0] / HF;
  const int M = in_sizes[2] / HF;
  const int E = in_sizes[3];
  const int NVR = idiv(N, VRANGE);  // node range count (2 for N=50000)

  // ---- workspace layout (nothing needs zeroing: counting sort writes every cell) ----
  char* wp = (char*)d_ws;
  float* part1 = (float*)wp; wp += (size_t)CS_GRID * 512 * 4;  // gn1 partials (2*256 per blk)
  float* part2 = (float*)wp; wp += (size_t)CS_GRID * 256 * 4;  // gn2 partials (2*128 per blk)
  int* cnt_e = (int*)wp; wp += (size_t)M * 4;
  int* cnt_v = (int*)wp; wp += (size_t)N * 4;
  int* off_e = (int*)wp; wp += (size_t)(M + 1) * 4;
  int* off_v = (int*)wp; wp += (size_t)(N + 1) * 4;
  unsigned short* by_h = (unsigned short*)wp; wp += ((size_t)E * 2 + 3) & ~(size_t)3;
  unsigned short* by_v = (unsigned short*)wp; wp += ((size_t)E * 2 + 3) & ~(size_t)3;
  int* part_e = (int*)wp; wp += 257 * 4;
  int* part_v = (int*)wp; wp += 257 * 4;
  float* sc1 = (float*)wp; wp += 256 * 4;
  float* sh1 = (float*)wp; wp += 256 * 4;
  float* sc2 = (float*)wp; wp += 128 * 4;
  float* sh2 = (float*)wp; wp += 128 * 4;
  wp = (char*)(((uintptr_t)wp + 255) & ~(uintptr_t)255);
  float* wqt  = (float*)wp; wp += (size_t)128 * 128 * 4;   // Wq^T * scale
  float* wcat = (float*)wp; wp += (size_t)128 * 256 * 4;   // [Wqk | Wv]
  float* h   = (float*)wp; wp += (size_t)N * HF * 4;       // sr1 out, += m_v, sr2 in; later c1
  float* h2  = (float*)wp; wp += (size_t)N * HF * 4;       // sr2 out = q; later z [M,256]
  float* xe  = (float*)wp; wp += (size_t)M * HF * 4;
  float* kvf = (float*)wp; wp += (size_t)M * 256 * 4;      // t1 fp32 alias / kv bf16
  float* z2  = (float*)wp; wp += (size_t)M * HF * 4;
  unsigned short* h16   = (unsigned short*)wp; wp += (size_t)N * HF * 2;  // sr1 bf16 shadow
  unsigned short* ho16  = (unsigned short*)wp; wp += (size_t)N * HF * 2;  // att out bf16
  unsigned short* m_e16 = (unsigned short*)wp; wp += (size_t)M * HF * 2;

  unsigned short* kv = (unsigned short*)kvf;   // [M][256] bf16
  float* t1  = kvf;                // her hidden [M,128] fp32 (dead before kv written)
  float* z   = h2;                 // [M,256] (h2 dead as q after att_fused)
  float* c1  = h;                  // [M,128] (h dead after sr2)

  // Histogram matrices alias h (dead until sr1): NB*M + NVR*NB*VPACK ints = 17.9MB < 25.6MB
  int* HE = (int*)h;
  int* HV = HE + (size_t)NB_CSR * M;

  // ---- CSR build: counting sort, zero device-scope atomics ----
  csr_hist<<<dim3(NB_CSR, 1 + NVR), 512, 0, stream>>>(node_idx, hedge_idx, E, M, HE, HV);
  csr_colscan<<<idiv(M + NVR * VPACK, 256), 256, 0, stream>>>(HE, HV, M, N, NVR, cnt_e, cnt_v);
  int nbE = idiv(M, SCAN_CHUNK);
  int nbV = idiv(N, SCAN_CHUNK);
  scanA2<<<nbE + nbV, 256, 0, stream>>>(cnt_e, M, nbE, part_e, cnt_v, N, part_v);
  scanB2<<<2, 256, 0, stream>>>(part_e, nbE, part_v, nbV);
  scanC2<<<nbE + nbV, 256, 0, stream>>>(cnt_e, M, nbE, part_e, off_e, cnt_v, N, nbV, part_v, off_v);
  csr_scatter<<<dim3(NB_CSR, 1 + NVR), 512, 0, stream>>>(node_idx, hedge_idx, E, M, HE, HV,
                                                         off_e, off_v, by_h, by_v);

  // wqt = Wq^T*scale, wcat[:,128:256] = Wv
  prep_att<<<64, 256, 0, stream>>>(att_Wq, att_Wv, wqt, wcat);

  dim3 blk(256);
  int nbxN = idiv(N, 64), nbxM = idiv(M, 64);

  // ---- Phase A (fused): sr1 (fp32 + bf16 shadow; overwrites HE/HV) || her1 || wcatK ----
  GArgs gsr1 = {x, sr_W1, sr_b1, h, N, HF, HF, 1, nullptr, nullptr, 0, HF, 0, h16, nbxN, nbxN * 2};
  GArgs gher1 = {x_e, her_W1, her_b1, t1, M, HF, HF, 1, nullptr, nullptr, 0, HF, 0, nullptr, nbxM, nbxM * 2};
  GArgs gwk = {att_Wk, wqt, nullptr, wcat, 128, 128, 128, 0, nullptr, nullptr, 0, 256, 0, nullptr, 2, 4};
  gemm64_multi<<<gsr1.nb + gher1.nb + gwk.nb, blk, 0, stream>>>(gsr1, gher1, gwk);

  // ---- Phase B (fused): her2 || seg_mean_e (bf16 gather) ----
  GArgs gher2 = {t1, her_W2, her_b2, xe, M, HF, HF, 0, nullptr, nullptr, 0, HF, 0, nullptr, nbxM, nbxM * 2};
  gemm_segmean<<<gher2.nb + idiv(M * 64, 256), blk, 0, stream>>>(gher2, h16, off_e, by_h, m_e16, M);

  // ---- Phase B2 (fused): kv projection [xe@Wqk | xe@Wv] bf16 || seg_mean_v_add ----
  GArgs gkv = {xe, wcat, nullptr, (float*)kv, M, HF, 256, 0, nullptr, nullptr, 0, 256, 1, nullptr, nbxM, nbxM * 4};
  gemm_segmeanv<<<gkv.nb + idiv(N * 64, 256), blk, 0, stream>>>(gkv, h, m_e16, off_v, by_v, N);

  // ---- Phase C: sr2 -> h2 (q) ----
  GArgs gsr2 = {h, sr_W2, sr_b2, h2, N, HF, HF, 1, nullptr, nullptr, 0, HF, 0, nullptr, nbxN, nbxN * 2};
  gemm64<<<gsr2.nb, blk, 0, stream>>>(gsr2);

  // fused attention (q = h2)
  att_fused<<<idiv(N * 64, 256), blk, 0, stream>>>(h2, kv, off_v, by_v, ho16, N);
  // min aggregation + concat (z overwrites h2)
  seg_min_z<<<idiv(M * 64, 256), blk, 0, stream>>>(ho16, off_e, by_h, xe, z, M);
  // gn1 stats (partials + finalize) -> ef linear(+act) -> gn2 stats
  colstats_part<<<CS_GRID, 1024, 0, stream>>>(z, M, 256, part1);
  colstats_fin<<<1, 256, 0, stream>>>(part1, CS_GRID, 256, gn1_w, gn1_b, gn1_a,
                                      1.f / (float)M, sc1, sh1);
  GArgs gef = {z, ef_W, ef_b, z2, M, 2 * HF, HF, 1, sc1, sh1, 0, HF, 0, nullptr, nbxM, nbxM * 2};
  gemm64<<<gef.nb, blk, 0, stream>>>(gef);
  colstats_part<<<CS_GRID, 1024, 0, stream>>>(z2, M, 128, part2);
  colstats_fin<<<1, 128, 0, stream>>>(part2, CS_GRID, 128, gn2_w, gn2_b, gn2_a,
                                      1.f / (float)M, sc2, sh2);
  // classifier
  GArgs gc1 = {z2, cls_W1, cls_b1, c1, M, HF, HF, 1, sc2, sh2, 1, HF, 0, nullptr, nbxM, nbxM * 2};
  gemm64<<<gc1.nb, blk, 0, stream>>>(gc1);
  GArgs gc2 = {c1, cls_W2, cls_b2, (float*)d_out, M, HF, 64, 0, nullptr, nullptr, 0, 64, 0, nullptr, nbxM, nbxM};
  gemm64<<<gc2.nb, blk, 0, stream>>>(gc2);
}

// Round 13
// 344.240 us; speedup vs baseline: 1.0203x; 1.0203x over previous
//
#include <hip/hip_runtime.h>
#include <float.h>
#include <math.h>

#define HF 128
#define SCAN_CHUNK 4096  // 256 threads x 16 elems
#define NB_CSR 128       // chunks for counting-sort CSR build
#define VPACK 12500      // packed (2-per-int) node bins per range: 25000 nodes / range
#define VRANGE (2 * VPACK)
#define CS_GRID 256      // colstats_part grid (per-block partials, no atomics)

static inline int idiv(int a, int b) { return (a + b - 1) / b; }

__device__ inline unsigned short f2bf(float x) {  // RNE float->bf16
  unsigned u = __float_as_uint(x);
  return (unsigned short)((u + 0x7fffu + ((u >> 16) & 1u)) >> 16);
}
__device__ inline unsigned packbf(float a, float b) {
  return (unsigned)f2bf(a) | ((unsigned)f2bf(b) << 16);
}
#define BFLO(w) __uint_as_float((w) << 16)
#define BFHI(w) __uint_as_float((w) & 0xffff0000u)

// ---------------- CSR build: LDS-histogram counting sort (ZERO device-scope atomics) ----------------
// Round-2 evidence: 1.2M global atomics = 24.7 G/s RMW wall. Per-chunk LDS histograms
// + column scan + scatter instead.

__global__ __launch_bounds__(512) void csr_hist(const int* __restrict__ nidx,
                                                const int* __restrict__ hidx,
                                                int E, int M,
                                                int* __restrict__ HE,
                                                int* __restrict__ HV) {
  __shared__ int bins[VPACK];
  int b = blockIdx.x, y = blockIdx.y, tid = threadIdx.x;
  int chunk = (E + NB_CSR - 1) / NB_CSR;
  int e0 = b * chunk;
  int e1 = e0 + chunk; if (e1 > E) e1 = E;
  if (y == 0) {
    for (int s = tid; s < M; s += 512) bins[s] = 0;
    __syncthreads();
    for (int e = e0 + tid; e < e1; e += 512) atomicAdd(&bins[hidx[e]], 1);
    __syncthreads();
    for (int s = tid; s < M; s += 512) HE[(size_t)b * M + s] = bins[s];
  } else {
    int R = (y - 1) * VRANGE;
    int* HVr = HV + ((size_t)(y - 1) * NB_CSR + b) * VPACK;
    for (int q = tid; q < VPACK; q += 512) bins[q] = 0;
    __syncthreads();
    for (int e = e0 + tid; e < e1; e += 512) {
      int v = nidx[e] - R;
      if ((unsigned)v < (unsigned)VRANGE) atomicAdd(&bins[v >> 1], (v & 1) ? 0x10000 : 1);
    }
    __syncthreads();
    for (int q = tid; q < VPACK; q += 512) HVr[q] = bins[q];
  }
}

// Per-segment exclusive scan over the NB_CSR chunks (in place) + dense counts.
__global__ __launch_bounds__(256) void csr_colscan(int* __restrict__ HE,
                                                   int* __restrict__ HV,
                                                   int M, int N, int NVR,
                                                   int* __restrict__ cnt_e,
                                                   int* __restrict__ cnt_v) {
  int col = blockIdx.x * 256 + threadIdx.x;
  if (col < M) {
    int run = 0;
    for (int b = 0; b < NB_CSR; ++b) {
      size_t i = (size_t)b * M + col;
      int t = HE[i]; HE[i] = run; run += t;
    }
    cnt_e[col] = run;
  } else if (col < M + NVR * VPACK) {
    int c = col - M;
    int r = c / VPACK, q = c - r * VPACK;
    int* HVr = HV + (size_t)r * NB_CSR * VPACK;
    int run = 0;
    for (int b = 0; b < NB_CSR; ++b) {
      size_t i = (size_t)b * VPACK + q;
      int t = HVr[i]; HVr[i] = run; run += t;
    }
    int node = r * VRANGE + 2 * q;
    if (node < N) cnt_v[node] = run & 0xffff;
    if (node + 1 < N) cnt_v[node + 1] = run >> 16;
  }
}

// Scatter: preload LDS bins with global base (off + chunk-exclusive), LDS-atomic rank.
__global__ __launch_bounds__(512) void csr_scatter(const int* __restrict__ nidx,
                                                   const int* __restrict__ hidx,
                                                   int E, int M,
                                                   const int* __restrict__ HE,
                                                   const int* __restrict__ HV,
                                                   const int* __restrict__ off_e,
                                                   const int* __restrict__ off_v,
                                                   unsigned short* __restrict__ by_h,
                                                   unsigned short* __restrict__ by_v) {
  __shared__ int bins[VPACK];
  int b = blockIdx.x, y = blockIdx.y, tid = threadIdx.x;
  int chunk = (E + NB_CSR - 1) / NB_CSR;
  int e0 = b * chunk;
  int e1 = e0 + chunk; if (e1 > E) e1 = E;
  if (y == 0) {
    for (int s = tid; s < M; s += 512) bins[s] = off_e[s] + HE[(size_t)b * M + s];
    __syncthreads();
    for (int e = e0 + tid; e < e1; e += 512) {
      int pos = atomicAdd(&bins[hidx[e]], 1);
      by_h[pos] = (unsigned short)nidx[e];
    }
  } else {
    int R = (y - 1) * VRANGE;
    const int* HVr = HV + ((size_t)(y - 1) * NB_CSR + b) * VPACK;
    for (int q = tid; q < VPACK; q += 512) bins[q] = HVr[q];
    __syncthreads();
    for (int e = e0 + tid; e < e1; e += 512) {
      int v = nidx[e];
      int vr = v - R;
      if ((unsigned)vr < (unsigned)VRANGE) {
        int old = atomicAdd(&bins[vr >> 1], (vr & 1) ? 0x10000 : 1);
        int rank = (vr & 1) ? (old >> 16) : (old & 0xffff);
        by_v[off_v[v] + rank] = (unsigned short)hidx[e];
      }
    }
  }
}

// ---- fused 3-phase multi-block exclusive scan over both dense count arrays ----

__global__ __launch_bounds__(256) void scanA2(const int* __restrict__ inE, int nE, int nbE,
                                              int* __restrict__ partE,
                                              const int* __restrict__ inV, int nV,
                                              int* __restrict__ partV) {
  const int* in; int n, b; int* partials;
  if ((int)blockIdx.x < nbE) { in = inE; n = nE; b = blockIdx.x; partials = partE; }
  else { in = inV; n = nV; b = blockIdx.x - nbE; partials = partV; }
  __shared__ int lds[256];
  int tid = threadIdx.x;
  int base = b * SCAN_CHUNK + tid * 16;
  int s = 0;
#pragma unroll
  for (int i = 0; i < 16; ++i) {
    int idx = base + i;
    if (idx < n) s += in[idx];
  }
  lds[tid] = s;
  __syncthreads();
  for (int off = 128; off; off >>= 1) {
    if (tid < off) lds[tid] += lds[tid + off];
    __syncthreads();
  }
  if (tid == 0) partials[b] = lds[0];
}

__global__ __launch_bounds__(256) void scanB2(int* __restrict__ partE, int nbE,
                                              int* __restrict__ partV, int nbV) {
  int* partials = (blockIdx.x == 0) ? partE : partV;
  int nb = (blockIdx.x == 0) ? nbE : nbV;
  __shared__ int lds[256];
  int tid = threadIdx.x;
  int v = (tid < nb) ? partials[tid] : 0;
  lds[tid] = v;
  __syncthreads();
  for (int off = 1; off < 256; off <<= 1) {
    int add = (tid >= off) ? lds[tid - off] : 0;
    __syncthreads();
    lds[tid] += add;
    __syncthreads();
  }
  if (tid < nb) partials[tid] = lds[tid] - v;  // exclusive
  if (tid == nb - 1) partials[nb] = lds[tid];  // total
}

__global__ __launch_bounds__(256) void scanC2(const int* __restrict__ inE, int nE, int nbE,
                                              const int* __restrict__ partE, int* __restrict__ outE,
                                              const int* __restrict__ inV, int nV, int nbV,
                                              const int* __restrict__ partV, int* __restrict__ outV) {
  const int* in; const int* partials; int* out; int n, b, nb;
  if ((int)blockIdx.x < nbE) { in = inE; n = nE; b = blockIdx.x; partials = partE; out = outE; nb = nbE; }
  else { in = inV; n = nV; b = blockIdx.x - nbE; partials = partV; out = outV; nb = nbV; }
  __shared__ int lds[256];
  int tid = threadIdx.x;
  int base = b * SCAN_CHUNK + tid * 16;
  int vals[16];
  int s = 0;
#pragma unroll
  for (int i = 0; i < 16; ++i) {
    int idx = base + i;
    int v = (idx < n) ? in[idx] : 0;
    vals[i] = s;
    s += v;
  }
  lds[tid] = s;
  __syncthreads();
  int own = s;
  for (int off = 1; off < 256; off <<= 1) {
    int add = (tid >= off) ? lds[tid - off] : 0;
    __syncthreads();
    lds[tid] += add;
    __syncthreads();
  }
  int excl = lds[tid] - own + partials[b];
#pragma unroll
  for (int i = 0; i < 16; ++i) {
    int idx = base + i;
    if (idx < n) out[idx] = excl + vals[i];
  }
  if (b == 0 && tid == 0) out[n] = partials[nb];
}

// wqt = Wq^T * (1/sqrt(128)) [score scale folded]; wcat[:,128:256] = Wv.
__global__ void prep_att(const float* __restrict__ Wq, const float* __restrict__ Wv,
                         float* __restrict__ wqt, float* __restrict__ wcat) {
  int i = blockIdx.x * blockDim.x + threadIdx.x;  // 128*128
  if (i >= 128 * 128) return;
  int r = i >> 7, c = i & 127;
  wqt[c * 128 + r] = Wq[i] * 0.08838834764831845f;
  wcat[r * 256 + 128 + c] = Wv[i];
}

// ---------------- GEMM: 64x64 tile, 4x4 micro, single LDS buffer (round-9 form) ----------------
// Round-10/11 evidence: LDS dbuf (occ 41->24%) regressed; register prefetch neutral.
// At ~41% occupancy wave-level TLP already hides staging latency -> simple form is best.

__device__ __forceinline__ void gemm64_body(const float* __restrict__ A,
                                            const float* __restrict__ W,
                                            const float* __restrict__ bias,
                                            float* __restrict__ out,
                                            int R, int K, int C, int act,
                                            const float* __restrict__ insc,
                                            const float* __restrict__ insh, int inact,
                                            int ldo, int obf16,
                                            unsigned short* __restrict__ out16,
                                            int bx, int by) {
  __shared__ __align__(16) float As[64][20];
  __shared__ __align__(16) float Bs[16][64];
  int tid = threadIdx.x;
  int tx = tid & 15;
  int ty = tid >> 4;
  int rowBase = bx * 64;
  int colBase = by * 64;

  float acc[4][4] = {};

  for (int k0 = 0; k0 < K; k0 += 16) {
    {
      int arow = tid >> 2, ac = (tid & 3) * 4;
      int gr = rowBase + arow;
      float4 av = make_float4(0.f, 0.f, 0.f, 0.f);
      if (gr < R) av = *(const float4*)(A + (size_t)gr * K + k0 + ac);
      if (insc) {
        float vv[4] = {av.x, av.y, av.z, av.w};
#pragma unroll
        for (int i = 0; i < 4; ++i) {
          float s = insc[k0 + ac + i], sh = insh[k0 + ac + i];
          float v = vv[i] * s + sh;
          if (inact) v = v > 0.f ? v : 0.01f * v;
          vv[i] = v;
        }
        av = make_float4(vv[0], vv[1], vv[2], vv[3]);
      }
      *(float4*)&As[arow][ac] = av;
    }
    {
      int bk = tid >> 4, bc = (tid & 15) * 4;
      *(float4*)&Bs[bk][bc] = *(const float4*)(W + (size_t)(k0 + bk) * C + colBase + bc);
    }
    __syncthreads();
#pragma unroll
    for (int kg = 0; kg < 16; kg += 4) {
      float af[4][4], bf[4][4];
#pragma unroll
      for (int i = 0; i < 4; ++i)
        *(float4*)af[i] = *(const float4*)&As[ty * 4 + i][kg];
#pragma unroll
      for (int kk = 0; kk < 4; ++kk)
        *(float4*)bf[kk] = *(const float4*)&Bs[kg + kk][tx * 4];
#pragma unroll
      for (int kk = 0; kk < 4; ++kk)
#pragma unroll
        for (int i = 0; i < 4; ++i)
#pragma unroll
          for (int j = 0; j < 4; ++j)
            acc[i][j] = fmaf(af[i][kk], bf[kk][j], acc[i][j]);
    }
    __syncthreads();
  }

#pragma unroll
  for (int i = 0; i < 4; ++i) {
    int r = rowBase + ty * 4 + i;
    if (r >= R) continue;
    float vals[4];
#pragma unroll
    for (int j = 0; j < 4; ++j) {
      float v = acc[i][j];
      if (bias) v += bias[colBase + tx * 4 + j];
      if (act) v = v > 0.f ? v : 0.01f * v;
      vals[j] = v;
    }
    if (obf16) {
      unsigned short* o16 = (unsigned short*)out;
      ushort4 w = make_ushort4(f2bf(vals[0]), f2bf(vals[1]), f2bf(vals[2]), f2bf(vals[3]));
      *(ushort4*)(o16 + (size_t)r * ldo + colBase + tx * 4) = w;
    } else {
      *(float4*)(out + (size_t)r * ldo + colBase + tx * 4) =
          make_float4(vals[0], vals[1], vals[2], vals[3]);
      if (out16) {
        uint2 w = make_uint2(packbf(vals[0], vals[1]), packbf(vals[2], vals[3]));
        *(uint2*)(out16 + (size_t)r * ldo + colBase + tx * 4) = w;
      }
    }
  }
}

struct GArgs {
  const float* A; const float* W; const float* bias; float* out;
  int R, K, C, act;
  const float* insc; const float* insh; int inact, ldo, obf16;
  unsigned short* out16;
  int nbx, nb;   // nbx = idiv(R,64); nb = nbx * ncols
};

__global__ __launch_bounds__(256) void gemm64(GArgs g) {
  gemm64_body(g.A, g.W, g.bias, g.out, g.R, g.K, g.C, g.act, g.insc, g.insh, g.inact,
              g.ldo, g.obf16, g.out16, blockIdx.x % g.nbx, blockIdx.x / g.nbx);
}

// Horizontal fusion of up to 3 independent GEMMs (identical body -> identical
// resources; block->arg selection is wave-uniform SGPR work).
__global__ __launch_bounds__(256) void gemm64_multi(GArgs g0, GArgs g1, GArgs g2) {
  int b = blockIdx.x;
  GArgs g = g0;
  if (b >= g0.nb) {
    b -= g0.nb;
    if (b < g1.nb) g = g1;
    else { b -= g1.nb; g = g2; }
  }
  gemm64_body(g.A, g.W, g.bias, g.out, g.R, g.K, g.C, g.act, g.insc, g.insh, g.inact,
              g.ldo, g.obf16, g.out16, b % g.nbx, b / g.nbx);
}

// ---------------- segment ops: one wave per segment; 4 x 16-lane groups, 8 feats/lane ----------------
// Round-6/7 evidence: 2-deep idx/data pipeline gained ~8us on the seg gathers (kept).

__device__ __forceinline__ void seg_mean_e_body(const unsigned short* __restrict__ h16,
                                                const int* __restrict__ off_e,
                                                const unsigned short* __restrict__ by_h,
                                                unsigned short* __restrict__ m_e16, int M, int bx) {
  int m = (bx * 256 + (int)threadIdx.x) >> 6;
  if (m >= M) return;
  int lane = threadIdx.x & 63;
  int g = lane >> 4;
  int fl = lane & 15;
  int s = off_e[m], e1 = off_e[m + 1];
  float4 a0 = make_float4(0.f, 0.f, 0.f, 0.f), a1 = a0;
  uint4 z4 = make_uint4(0, 0, 0, 0);
  int j = s + g;
  int iC = (j + 8 < e1) ? by_h[j + 8] : 0;
  uint4 hwA = z4, hwB = z4;
  if (j < e1) {
    int i0 = by_h[j];
    hwA = *(const uint4*)(h16 + (size_t)i0 * HF + fl * 8);
  }
  if (j + 4 < e1) {
    int i1 = by_h[j + 4];
    hwB = *(const uint4*)(h16 + (size_t)i1 * HF + fl * 8);
  }
  while (j < e1) {
    uint4 hwC = z4;
    if (j + 8 < e1) hwC = *(const uint4*)(h16 + (size_t)iC * HF + fl * 8);
    int iD = (j + 12 < e1) ? by_h[j + 12] : 0;
    a0.x += BFLO(hwA.x); a0.y += BFHI(hwA.x); a0.z += BFLO(hwA.y); a0.w += BFHI(hwA.y);
    a1.x += BFLO(hwA.z); a1.y += BFHI(hwA.z); a1.z += BFLO(hwA.w); a1.w += BFHI(hwA.w);
    hwA = hwB; hwB = hwC; iC = iD;
    j += 4;
  }
#pragma unroll
  for (int mask = 16; mask <= 32; mask <<= 1) {
    a0.x += __shfl_xor(a0.x, mask); a0.y += __shfl_xor(a0.y, mask);
    a0.z += __shfl_xor(a0.z, mask); a0.w += __shfl_xor(a0.w, mask);
    a1.x += __shfl_xor(a1.x, mask); a1.y += __shfl_xor(a1.y, mask);
    a1.z += __shfl_xor(a1.z, mask); a1.w += __shfl_xor(a1.w, mask);
  }
  if (g == 0) {
    int cnt = e1 - s;
    float r = 1.f / (float)(cnt > 0 ? cnt : 1);
    uint4 w = make_uint4(packbf(a0.x * r, a0.y * r), packbf(a0.z * r, a0.w * r),
                         packbf(a1.x * r, a1.y * r), packbf(a1.z * r, a1.w * r));
    *(uint4*)(m_e16 + (size_t)m * HF + fl * 8) = w;
  }
}

// Phase-B fusion: her2 GEMM blocks + seg_mean_e gather blocks (complementary pipes).
__global__ __launch_bounds__(256) void gemm_segmean(GArgs g,
                                                    const unsigned short* __restrict__ h16,
                                                    const int* __restrict__ off_e,
                                                    const unsigned short* __restrict__ by_h,
                                                    unsigned short* __restrict__ m_e16, int M) {
  int b = blockIdx.x;
  if (b < g.nb) {
    gemm64_body(g.A, g.W, g.bias, g.out, g.R, g.K, g.C, g.act, g.insc, g.insh, g.inact,
                g.ldo, g.obf16, g.out16, b % g.nbx, b / g.nbx);
    return;
  }
  seg_mean_e_body(h16, off_e, by_h, m_e16, M, b - g.nb);
}

__global__ __launch_bounds__(256) void seg_mean_v_add(float* __restrict__ h,
                                                      const unsigned short* __restrict__ m_e16,
                                                      const int* __restrict__ off_v,
                                                      const unsigned short* __restrict__ by_v,
                                                      int N) {
  int n = (blockIdx.x * blockDim.x + threadIdx.x) >> 6;
  if (n >= N) return;
  int lane = threadIdx.x & 63;
  int g = lane >> 4;
  int fl = lane & 15;
  int s = off_v[n], e1 = off_v[n + 1];
  float4 a0 = make_float4(0.f, 0.f, 0.f, 0.f), a1 = a0;
  uint4 z4 = make_uint4(0, 0, 0, 0);
  int j = s + g;
  int iC = (j + 8 < e1) ? by_v[j + 8] : 0;
  uint4 hwA = z4, hwB = z4;
  if (j < e1) {
    int i0 = by_v[j];
    hwA = *(const uint4*)(m_e16 + (size_t)i0 * HF + fl * 8);
  }
  if (j + 4 < e1) {
    int i1 = by_v[j + 4];
    hwB = *(const uint4*)(m_e16 + (size_t)i1 * HF + fl * 8);
  }
  while (j < e1) {
    uint4 hwC = z4;
    if (j + 8 < e1) hwC = *(const uint4*)(m_e16 + (size_t)iC * HF + fl * 8);
    int iD = (j + 12 < e1) ? by_v[j + 12] : 0;
    a0.x += BFLO(hwA.x); a0.y += BFHI(hwA.x); a0.z += BFLO(hwA.y); a0.w += BFHI(hwA.y);
    a1.x += BFLO(hwA.z); a1.y += BFHI(hwA.z); a1.z += BFLO(hwA.w); a1.w += BFHI(hwA.w);
    hwA = hwB; hwB = hwC; iC = iD;
    j += 4;
  }
#pragma unroll
  for (int mask = 16; mask <= 32; mask <<= 1) {
    a0.x += __shfl_xor(a0.x, mask); a0.y += __shfl_xor(a0.y, mask);
    a0.z += __shfl_xor(a0.z, mask); a0.w += __shfl_xor(a0.w, mask);
    a1.x += __shfl_xor(a1.x, mask); a1.y += __shfl_xor(a1.y, mask);
    a1.z += __shfl_xor(a1.z, mask); a1.w += __shfl_xor(a1.w, mask);
  }
  if (g == 0) {
    int cnt = e1 - s;
    float r = 1.f / (float)(cnt > 0 ? cnt : 1);
    float* hp = h + (size_t)n * HF + fl * 8;
    float4 h0 = *(const float4*)hp;
    float4 h1 = *(const float4*)(hp + 4);
    *(float4*)hp = make_float4(h0.x + a0.x * r, h0.y + a0.y * r, h0.z + a0.z * r, h0.w + a0.w * r);
    *(float4*)(hp + 4) = make_float4(h1.x + a1.x * r, h1.y + a1.y * r, h1.z + a1.z * r, h1.w + a1.w * r);
  }
}

// Fused GAT attention: one wave per node; q = h2 (fp32, score scale pre-folded into Wqk);
// kv bf16 [M][256]; software prefetch + defer-max rescale (THR=8).
// Round-7/8 evidence: this 4x16 one-deep form is the measured optimum (41.6us). Kept.
__global__ __launch_bounds__(256) void att_fused(const float* __restrict__ q,
                                                 const unsigned short* __restrict__ kv,
                                                 const int* __restrict__ off_v,
                                                 const unsigned short* __restrict__ by_v,
                                                 unsigned short* __restrict__ ho16, int N) {
  int n = (blockIdx.x * blockDim.x + threadIdx.x) >> 6;
  if (n >= N) return;
  int lane = threadIdx.x & 63;
  int g = lane >> 4;
  int fl = lane & 15;
  int s0 = off_v[n], s1 = off_v[n + 1];
  const float* qp = q + (size_t)n * HF + fl * 8;
  float4 q0 = *(const float4*)qp;
  float4 q1 = *(const float4*)(qp + 4);
  float m = -INFINITY, l = 0.f;
  float4 a0 = make_float4(0.f, 0.f, 0.f, 0.f), a1 = a0;
  int j = s0 + g;
  uint4 kw = make_uint4(0, 0, 0, 0), vw = kw;
  if (j < s1) {
    const unsigned short* base = kv + (size_t)by_v[j] * 256 + fl * 8;
    kw = *(const uint4*)base;
    vw = *(const uint4*)(base + 128);
  }
  while (j < s1) {
    int jn = j + 4;
    uint4 kw2 = make_uint4(0, 0, 0, 0), vw2 = kw2;
    if (jn < s1) {
      const unsigned short* b2 = kv + (size_t)by_v[jn] * 256 + fl * 8;
      kw2 = *(const uint4*)b2;
      vw2 = *(const uint4*)(b2 + 128);
    }
    float d = q0.x * BFLO(kw.x) + q0.y * BFHI(kw.x) + q0.z * BFLO(kw.y) + q0.w * BFHI(kw.y)
            + q1.x * BFLO(kw.z) + q1.y * BFHI(kw.z) + q1.z * BFLO(kw.w) + q1.w * BFHI(kw.w);
    d += __shfl_xor(d, 1);
    d += __shfl_xor(d, 2);
    d += __shfl_xor(d, 4);
    d += __shfl_xor(d, 8);
    d = d > 0.f ? d : 0.2f * d;   // scale already folded into Wqk
    if (d > m + 8.f) {
      float sc = __expf(m - d);   // first edge: exp(-inf)=0 zeroes l,a
      l *= sc;
      a0.x *= sc; a0.y *= sc; a0.z *= sc; a0.w *= sc;
      a1.x *= sc; a1.y *= sc; a1.z *= sc; a1.w *= sc;
      m = d;
    }
    float p = __expf(d - m);
    l += p;
    a0.x += p * BFLO(vw.x); a0.y += p * BFHI(vw.x);
    a0.z += p * BFLO(vw.y); a0.w += p * BFHI(vw.y);
    a1.x += p * BFLO(vw.z); a1.y += p * BFHI(vw.z);
    a1.z += p * BFLO(vw.w); a1.w += p * BFHI(vw.w);
    kw = kw2; vw = vw2; j = jn;
  }
#pragma unroll
  for (int mask = 16; mask <= 32; mask <<= 1) {
    float m2 = __shfl_xor(m, mask);
    float l2 = __shfl_xor(l, mask);
    float b0x = __shfl_xor(a0.x, mask), b0y = __shfl_xor(a0.y, mask);
    float b0z = __shfl_xor(a0.z, mask), b0w = __shfl_xor(a0.w, mask);
    float b1x = __shfl_xor(a1.x, mask), b1y = __shfl_xor(a1.y, mask);
    float b1z = __shfl_xor(a1.z, mask), b1w = __shfl_xor(a1.w, mask);
    float mn = fmaxf(fmaxf(m, m2), -1e30f);
    float ea = __expf(m - mn), eb = __expf(m2 - mn);
    l = l * ea + l2 * eb;
    a0.x = a0.x * ea + b0x * eb; a0.y = a0.y * ea + b0y * eb;
    a0.z = a0.z * ea + b0z * eb; a0.w = a0.w * ea + b0w * eb;
    a1.x = a1.x * ea + b1x * eb; a1.y = a1.y * ea + b1y * eb;
    a1.z = a1.z * ea + b1z * eb; a1.w = a1.w * ea + b1w * eb;
    m = fmaxf(m, m2);
  }
  if (g == 0) {
    float inv = 1.f / fmaxf(l, 1e-16f);
    uint4 w = make_uint4(packbf(a0.x * inv, a0.y * inv), packbf(a0.z * inv, a0.w * inv),
                         packbf(a1.x * inv, a1.y * inv), packbf(a1.z * inv, a1.w * inv));
    *(uint4*)(ho16 + (size_t)n * HF + fl * 8) = w;
  }
}

// z[m][0:128] = segment_min(ho16[node]) (0 if empty); z[m][128:256] = xe[m]
__global__ __launch_bounds__(256) void seg_min_z(const unsigned short* __restrict__ ho16,
                                                 const int* __restrict__ off_e,
                                                 const unsigned short* __restrict__ by_h,
                                                 const float* __restrict__ xe,
                                                 float* __restrict__ z, int M) {
  int m = (blockIdx.x * blockDim.x + threadIdx.x) >> 6;
  if (m >= M) return;
  int lane = threadIdx.x & 63;
  int g = lane >> 4;
  int fl = lane & 15;
  int s = off_e[m], e1 = off_e[m + 1];
  float4 a0 = make_float4(FLT_MAX, FLT_MAX, FLT_MAX, FLT_MAX), a1 = a0;
  uint4 z4 = make_uint4(0, 0, 0, 0);
  int j = s + g;
  int iC = (j + 8 < e1) ? by_h[j + 8] : 0;
  uint4 hwA = z4, hwB = z4;
  if (j < e1) {
    int i0 = by_h[j];
    hwA = *(const uint4*)(ho16 + (size_t)i0 * HF + fl * 8);
  }
  if (j + 4 < e1) {
    int i1 = by_h[j + 4];
    hwB = *(const uint4*)(ho16 + (size_t)i1 * HF + fl * 8);
  }
  while (j < e1) {
    uint4 hwC = z4;
    if (j + 8 < e1) hwC = *(const uint4*)(ho16 + (size_t)iC * HF + fl * 8);
    int iD = (j + 12 < e1) ? by_h[j + 12] : 0;
    a0.x = fminf(a0.x, BFLO(hwA.x)); a0.y = fminf(a0.y, BFHI(hwA.x));
    a0.z = fminf(a0.z, BFLO(hwA.y)); a0.w = fminf(a0.w, BFHI(hwA.y));
    a1.x = fminf(a1.x, BFLO(hwA.z)); a1.y = fminf(a1.y, BFHI(hwA.z));
    a1.z = fminf(a1.z, BFLO(hwA.w)); a1.w = fminf(a1.w, BFHI(hwA.w));
    hwA = hwB; hwB = hwC; iC = iD;
    j += 4;
  }
#pragma unroll
  for (int mask = 16; mask <= 32; mask <<= 1) {
    a0.x = fminf(a0.x, __shfl_xor(a0.x, mask)); a0.y = fminf(a0.y, __shfl_xor(a0.y, mask));
    a0.z = fminf(a0.z, __shfl_xor(a0.z, mask)); a0.w = fminf(a0.w, __shfl_xor(a0.w, mask));
    a1.x = fminf(a1.x, __shfl_xor(a1.x, mask)); a1.y = fminf(a1.y, __shfl_xor(a1.y, mask));
    a1.z = fminf(a1.z, __shfl_xor(a1.z, mask)); a1.w = fminf(a1.w, __shfl_xor(a1.w, mask));
  }
  if (g == 0) {
    bool nz = (e1 > s);
    float* op = z + (size_t)m * 256 + fl * 8;
    *(float4*)op = nz ? a0 : make_float4(0.f, 0.f, 0.f, 0.f);
    *(float4*)(op + 4) = nz ? a1 : make_float4(0.f, 0.f, 0.f, 0.f);
  } else if (g == 1) {
    const float* xp = xe + (size_t)m * HF + fl * 8;
    float* op = z + (size_t)m * 256 + 128 + fl * 8;
    *(float4*)op = *(const float4*)xp;
    *(float4*)(op + 4) = *(const float4*)(xp + 4);
  }
}

// ---------------- GraphNorm stats: two-kernel deterministic reduction ----------------

__global__ __launch_bounds__(1024) void colstats_part(const float* __restrict__ z, int rows, int C,
                                                      float* __restrict__ part) {
  int tid = threadIdx.x;
  int RL = 1024 / C;
  int col = tid & (C - 1);
  int ro = tid / C;
  float s1 = 0.f, s2 = 0.f;
  for (int r = blockIdx.x * RL + ro; r < rows; r += gridDim.x * RL) {
    float v = z[(size_t)r * C + col];
    s1 += v;
    s2 += v * v;
  }
  __shared__ float l1[1024], l2[1024];
  l1[tid] = s1;
  l2[tid] = s2;
  __syncthreads();
  for (int off = 512; off >= C; off >>= 1) {
    if (tid < off) { l1[tid] += l1[tid + off]; l2[tid] += l2[tid + off]; }
    __syncthreads();
  }
  if (tid < C) {
    part[(size_t)blockIdx.x * 2 * C + tid] = l1[tid];
    part[(size_t)blockIdx.x * 2 * C + C + tid] = l2[tid];
  }
}

__global__ void colstats_fin(const float* __restrict__ part, int nb, int C,
                             const float* __restrict__ w, const float* __restrict__ b,
                             const float* __restrict__ a, float invrows,
                             float* __restrict__ sc, float* __restrict__ sh) {
  int col = threadIdx.x;
  if (col >= C) return;
  float s1 = 0.f, s2 = 0.f;
#pragma unroll 8
  for (int i = 0; i < nb; ++i) {
    s1 += part[(size_t)i * 2 * C + col];
    s2 += part[(size_t)i * 2 * C + C + col];
  }
  float mu = s1 * invrows;
  float ex2 = s2 * invrows;
  float av = a[col];
  float var = ex2 - 2.f * av * mu * mu + av * av * mu * mu;
  float s = w[col] * rsqrtf(var + 1e-5f);
  sc[col] = s;
  sh[col] = b[col] - av * mu * s;
}

// ---------------- launch ----------------

extern "C" void kernel_launch(void* const* d_in, const int* in_sizes, int n_in,
                              void* d_out, int out_size, void* d_ws, size_t ws_size,
                              hipStream_t stream) {
  const float* x        = (const float*)d_in[0];
  const float* x_e      = (const float*)d_in[2];
  const int*   node_idx = (const int*)d_in[3];
  const int*   hedge_idx= (const int*)d_in[4];
  const float* her_W1   = (const float*)d_in[5];
  const float* her_b1   = (const float*)d_in[6];
  const float* her_W2   = (const float*)d_in[7];
  const float* her_b2   = (const float*)d_in[8];
  const float* sr_W1    = (const float*)d_in[9];
  const float* sr_b1    = (const float*)d_in[10];
  const float* sr_W2    = (const float*)d_in[11];
  const float* sr_b2    = (const float*)d_in[12];
  const float* att_Wq   = (const float*)d_in[13];
  const float* att_Wk   = (const float*)d_in[14];
  const float* att_Wv   = (const float*)d_in[15];
  const float* ef_W     = (const float*)d_in[16];
  const float* ef_b     = (const float*)d_in[17];
  const float* gn1_w    = (const float*)d_in[18];
  const float* gn1_b    = (const float*)d_in[19];
  const float* gn1_a    = (const float*)d_in[20];
  const float* gn2_w    = (const float*)d_in[21];
  const float* gn2_b    = (const float*)d_in[22];
  const float* gn2_a    = (const float*)d_in[23];
  const float* cls_W1   = (const float*)d_in[24];
  const float* cls_b1   = (const float*)d_in[25];
  const float* cls_W2   = (const float*)d_in[26];
  const float* cls_b2   = (const float*)d_in[27];

  const int N = in_sizes[0] / HF;
  const int M = in_sizes[2] / HF;
  const int E = in_sizes[3];
  const int NVR = idiv(N, VRANGE);  // node range count (2 for N=50000)

  // ---- workspace layout (nothing needs zeroing: counting sort writes every cell) ----
  char* wp = (char*)d_ws;
  float* part1 = (float*)wp; wp += (size_t)CS_GRID * 512 * 4;  // gn1 partials (2*256 per blk)
  float* part2 = (float*)wp; wp += (size_t)CS_GRID * 256 * 4;  // gn2 partials (2*128 per blk)
  int* cnt_e = (int*)wp; wp += (size_t)M * 4;
  int* cnt_v = (int*)wp; wp += (size_t)N * 4;
  int* off_e = (int*)wp; wp += (size_t)(M + 1) * 4;
  int* off_v = (int*)wp; wp += (size_t)(N + 1) * 4;
  unsigned short* by_h = (unsigned short*)wp; wp += ((size_t)E * 2 + 3) & ~(size_t)3;
  unsigned short* by_v = (unsigned short*)wp; wp += ((size_t)E * 2 + 3) & ~(size_t)3;
  int* part_e = (int*)wp; wp += 257 * 4;
  int* part_v = (int*)wp; wp += 257 * 4;
  float* sc1 = (float*)wp; wp += 256 * 4;
  float* sh1 = (float*)wp; wp += 256 * 4;
  float* sc2 = (float*)wp; wp += 128 * 4;
  float* sh2 = (float*)wp; wp += 128 * 4;
  wp = (char*)(((uintptr_t)wp + 255) & ~(uintptr_t)255);
  float* wqt  = (float*)wp; wp += (size_t)128 * 128 * 4;   // Wq^T * scale
  float* wcat = (float*)wp; wp += (size_t)128 * 256 * 4;   // [Wqk | Wv]
  float* h   = (float*)wp; wp += (size_t)N * HF * 4;       // sr1 out, += m_v, sr2 in; later c1
  float* h2  = (float*)wp; wp += (size_t)N * HF * 4;       // sr2 out = q; later z [M,256]
  float* xe  = (float*)wp; wp += (size_t)M * HF * 4;
  float* kvf = (float*)wp; wp += (size_t)M * 256 * 4;      // t1 fp32 alias / kv bf16
  float* z2  = (float*)wp; wp += (size_t)M * HF * 4;
  unsigned short* h16   = (unsigned short*)wp; wp += (size_t)N * HF * 2;  // sr1 bf16 shadow
  unsigned short* ho16  = (unsigned short*)wp; wp += (size_t)N * HF * 2;  // att out bf16
  unsigned short* m_e16 = (unsigned short*)wp; wp += (size_t)M * HF * 2;

  unsigned short* kv = (unsigned short*)kvf;   // [M][256] bf16
  float* t1  = kvf;                // her hidden [M,128] fp32 (dead before kv written)
  float* z   = h2;                 // [M,256] (h2 dead as q after att_fused)
  float* c1  = h;                  // [M,128] (h dead after sr2)

  // Histogram matrices alias h (dead until sr1): NB*M + NVR*NB*VPACK ints = 17.9MB < 25.6MB
  int* HE = (int*)h;
  int* HV = HE + (size_t)NB_CSR * M;

  // ---- CSR build: counting sort, zero device-scope atomics ----
  csr_hist<<<dim3(NB_CSR, 1 + NVR), 512, 0, stream>>>(node_idx, hedge_idx, E, M, HE, HV);
  csr_colscan<<<idiv(M + NVR * VPACK, 256), 256, 0, stream>>>(HE, HV, M, N, NVR, cnt_e, cnt_v);
  int nbE = idiv(M, SCAN_CHUNK);
  int nbV = idiv(N, SCAN_CHUNK);
  scanA2<<<nbE + nbV, 256, 0, stream>>>(cnt_e, M, nbE, part_e, cnt_v, N, part_v);
  scanB2<<<2, 256, 0, stream>>>(part_e, nbE, part_v, nbV);
  scanC2<<<nbE + nbV, 256, 0, stream>>>(cnt_e, M, nbE, part_e, off_e, cnt_v, N, nbV, part_v, off_v);
  csr_scatter<<<dim3(NB_CSR, 1 + NVR), 512, 0, stream>>>(node_idx, hedge_idx, E, M, HE, HV,
                                                         off_e, off_v, by_h, by_v);

  // wqt = Wq^T*scale, wcat[:,128:256] = Wv
  prep_att<<<64, 256, 0, stream>>>(att_Wq, att_Wv, wqt, wcat);

  dim3 blk(256);
  int nbxN = idiv(N, 64), nbxM = idiv(M, 64);

  // ---- Phase A (fused): sr1 (fp32 + bf16 shadow; overwrites HE/HV) || her1 || wcatK ----
  GArgs gsr1 = {x, sr_W1, sr_b1, h, N, HF, HF, 1, nullptr, nullptr, 0, HF, 0, h16, nbxN, nbxN * 2};
  GArgs gher1 = {x_e, her_W1, her_b1, t1, M, HF, HF, 1, nullptr, nullptr, 0, HF, 0, nullptr, nbxM, nbxM * 2};
  GArgs gwk = {att_Wk, wqt, nullptr, wcat, 128, 128, 128, 0, nullptr, nullptr, 0, 256, 0, nullptr, 2, 4};
  gemm64_multi<<<gsr1.nb + gher1.nb + gwk.nb, blk, 0, stream>>>(gsr1, gher1, gwk);

  // ---- Phase B (fused): her2 || seg_mean_e (bf16 gather) ----
  GArgs gher2 = {t1, her_W2, her_b2, xe, M, HF, HF, 0, nullptr, nullptr, 0, HF, 0, nullptr, nbxM, nbxM * 2};
  gemm_segmean<<<gher2.nb + idiv(M * 64, 256), blk, 0, stream>>>(gher2, h16, off_e, by_h, m_e16, M);

  seg_mean_v_add<<<idiv(N * 64, 256), blk, 0, stream>>>(h, m_e16, off_v, by_v, N);

  // ---- Phase C (fused): sr2 -> h2 (q) || kv projection [xe@Wqk | xe@Wv] bf16 ----
  // (Round-12 evidence: moving kv into B2 regressed — kv rides free in sr2's stall
  //  slots here; round-9 arrangement is the measured optimum.)
  GArgs gsr2 = {h, sr_W2, sr_b2, h2, N, HF, HF, 1, nullptr, nullptr, 0, HF, 0, nullptr, nbxN, nbxN * 2};
  GArgs gkv = {xe, wcat, nullptr, (float*)kv, M, HF, 256, 0, nullptr, nullptr, 0, 256, 1, nullptr, nbxM, nbxM * 4};
  gemm64_multi<<<gsr2.nb + gkv.nb, blk, 0, stream>>>(gsr2, gkv, gkv);

  // fused attention (q = h2)
  att_fused<<<idiv(N * 64, 256), blk, 0, stream>>>(h2, kv, off_v, by_v, ho16, N);
  // min aggregation + concat (z overwrites h2)
  seg_min_z<<<idiv(M * 64, 256), blk, 0, stream>>>(ho16, off_e, by_h, xe, z, M);
  // gn1 stats (partials + finalize) -> ef linear(+act) -> gn2 stats
  colstats_part<<<CS_GRID, 1024, 0, stream>>>(z, M, 256, part1);
  colstats_fin<<<1, 256, 0, stream>>>(part1, CS_GRID, 256, gn1_w, gn1_b, gn1_a,
                                      1.f / (float)M, sc1, sh1);
  GArgs gef = {z, ef_W, ef_b, z2, M, 2 * HF, HF, 1, sc1, sh1, 0, HF, 0, nullptr, nbxM, nbxM * 2};
  gemm64<<<gef.nb, blk, 0, stream>>>(gef);
  colstats_part<<<CS_GRID, 1024, 0, stream>>>(z2, M, 128, part2);
  colstats_fin<<<1, 128, 0, stream>>>(part2, CS_GRID, 128, gn2_w, gn2_b, gn2_a,
                                      1.f / (float)M, sc2, sh2);
  // classifier
  GArgs gc1 = {z2, cls_W1, cls_b1, c1, M, HF, HF, 1, sc2, sh2, 1, HF, 0, nullptr, nbxM, nbxM * 2};
  gemm64<<<gc1.nb, blk, 0, stream>>>(gc1);
  GArgs gc2 = {c1, cls_W2, cls_b2, (float*)d_out, M, HF, 64, 0, nullptr, nullptr, 0, 64, 0, nullptr, nbxM, nbxM};
  gemm64<<<gc2.nb, blk, 0, stream>>>(gc2);
}